// Round 9
// baseline (75.869 us; speedup 1.0000x reference)
//
#include <hip/hip_runtime.h>

#define NUM_CLASSES 80
#define CQ 20           // cls channels per quarter
#define R1 8            // REG_MAX + 1
#define HW 4096         // H*W
#define BLOCK 512       // 4 quarters x 128 threads
#define APB 512         // anchors per block (128 groups x 4 anchors)

// fast hardware transcendentals (outputs are sums of 262K O(1) terms,
// absmax threshold 122.88 -- 2-ulp native math is noise)
__device__ __forceinline__ float fexp(float x) { return __expf(x); }
__device__ __forceinline__ float flog(float x) { return __logf(x); }
__device__ __forceinline__ float frcp(float x) { return __builtin_amdgcn_rcpf(x); }

// NCH channel-strided float4 loads (16 B/lane = 1 KB/wave-load).
template<int C0, int NCH>
__device__ __forceinline__ void ldn(float4 (&d)[NCH], const float* __restrict__ u,
                                    uint32_t e) {
    #pragma unroll
    for (int j = 0; j < NCH; ++j)
        d[j] = *reinterpret_cast<const float4*>(u + (uint32_t)((C0 + j) * HW) + e);
}

__device__ __forceinline__ void cls1(float x, float& xm, float& ns) {
    xm = fmaxf(xm, x);
    float e  = fexp(-x);            // exp(-x)
    float s  = frcp(1.0f + e);      // sigmoid
    float sp = x - flog(s);         // softplus(x)
    ns = fmaf(sp * s, s, ns);
}

// 5 channels x 4 anchors; all indices compile-time
__device__ __forceinline__ void cls5x4(const float4 (&d)[5],
                                       float (&xm)[4], float (&ns)[4]) {
    #pragma unroll
    for (int j = 0; j < 5; ++j) {
        cls1(d[j].x, xm[0], ns[0]);
        cls1(d[j].y, xm[1], ns[1]);
        cls1(d[j].z, xm[2], ns[2]);
        cls1(d[j].w, xm[3], ns[3]);
    }
}

// one bbox side for one anchor: softmax-integral corner + DFL term
__device__ __forceinline__ void box8(const float (&xk)[8], float dk,
                                     float& corner, float& dsum) {
    float m = -INFINITY;
    #pragma unroll
    for (int j = 0; j < 8; ++j) m = fmaxf(m, xk[j]);
    float se = 0.0f, swe = 0.0f;
    #pragma unroll
    for (int j = 0; j < 8; ++j) {
        float e = fexp(xk[j] - m);
        se += e;
        swe = fmaf(e, (float)j, swe);
    }
    corner = swe * frcp(se);
    const float lse = m + flog(se);     // logsumexp

    // DFL: runtime bin -> unrolled compare-select (no scratch)
    float d = fminf(fmaxf(dk, 0.0f), (float)(R1 - 1) - 0.1f);
    int tl = (int)d;                    // d >= 0: floor == trunc
    int tr = tl + 1; if (tr > R1 - 1) tr = R1 - 1;
    float x_tl = xk[0], x_tr = xk[0];
    #pragma unroll
    for (int j = 1; j < 8; ++j) {
        if (j == tl) x_tl = xk[j];
        if (j == tr) x_tr = xk[j];
    }
    dsum += (lse - x_tl) * ((float)(tl + 1) - d) + (lse - x_tr) * (d - (float)tl);
}

// this quarter's side (8 channels) for 4 anchors
__device__ __forceinline__ void box8x4(const float4 (&d)[8], const float (&dk)[4],
                                       float (&cor)[4], float (&ds)[4]) {
    float xk[8];
    #pragma unroll
    for (int j = 0; j < 8; ++j) xk[j] = d[j].x;
    box8(xk, dk[0], cor[0], ds[0]);
    #pragma unroll
    for (int j = 0; j < 8; ++j) xk[j] = d[j].y;
    box8(xk, dk[1], cor[1], ds[1]);
    #pragma unroll
    for (int j = 0; j < 8; ++j) xk[j] = d[j].z;
    box8(xk, dk[2], cor[2], ds[2]);
    #pragma unroll
    for (int j = 0; j < 8; ++j) xk[j] = d[j].w;
    box8(xk, dk[3], cor[3], ds[3]);
}

__global__ __launch_bounds__(BLOCK)
__attribute__((amdgpu_waves_per_eu(4, 4)))   // 128-VGPR budget, 4 waves/SIMD
void nanodet_loss_kernel(
    const float* __restrict__ anchors,       // [N,4]
    const float* __restrict__ cls_score,     // [B,C,H,W]
    const float* __restrict__ bbox_pred,     // [B,4*R1,H,W]
    const float* __restrict__ label_weights, // [N]
    const float* __restrict__ bbox_targets,  // [N,4]
    const int*   __restrict__ labels,        // [N]
    const int*   __restrict__ nts_p,         // [1]
    const int*   __restrict__ stride_p,      // [1]
    float* __restrict__ out)
{
    const int tib = threadIdx.x;
    const int q   = tib >> 7;                // quarter: cls [20q,20q+20), side q
    const int g   = tib & 127;               // anchor group in block
    const int blk = blockIdx.x;
    const int b   = blk >> 3;                // image (uniform per block)
    const int hw0 = (blk & 7) * APB;         // window start (uniform)
    const int e   = 4 * g;                   // element offset in window
    const int n0  = blk * APB + e;           // first of this thread's 4 anchors

    const float inv_str = frcp((float)stride_p[0]);
    const float inv_nts = frcp((float)nts_p[0]);

    // quarter-uniform bases (SGPR) + per-thread element offset
    const float* cls_q = cls_score + (size_t)b * NUM_CLASSES * HW
                                   + (size_t)(q * CQ) * HW + hw0;
    const float* box_q = bbox_pred + (size_t)b * (4 * R1) * HW
                                   + (size_t)(q * R1) * HW + hw0;
    const uint32_t ue = (uint32_t)e;

    // ---- early scalar loads ----
    const int4 lab4 = *(const int4*)(labels + n0);
    int labv[4] = {lab4.x, lab4.y, lab4.z, lab4.w};

    // label-logit gather (this quarter's channel range, else dummy ch 0)
    float xlab[4];
    #pragma unroll
    for (int i = 0; i < 4; ++i) {
        const int lc = labv[i];
        const bool own = (lc >= q * CQ) && (lc < (q + 1) * CQ) && (lc < NUM_CLASSES);
        const int ch = own ? (lc - q * CQ) : 0;
        xlab[i] = cls_q[(uint32_t)ch * HW + ue + i];
    }

    // ---- cls pipeline: 4 phases x 5 channels, 2 buffers ----
    float4 A[5], B[5];
    float xm[4] = {-INFINITY, -INFINITY, -INFINITY, -INFINITY};
    float ns[4] = {0.0f, 0.0f, 0.0f, 0.0f};

    ldn<0, 5>(A, cls_q, ue);
    ldn<5, 5>(B, cls_q, ue);
    cls5x4(A, xm, ns);  ldn<10, 5>(A, cls_q, ue);
    cls5x4(B, xm, ns);  ldn<15, 5>(B, cls_q, ue);
    cls5x4(A, xm, ns);

    // issue this quarter's bbox side (8 channels) + geometry loads;
    // latency hides under the last cls phase + geometry VALU
    float4 X[8];
    ldn<0, 8>(X, box_q, ue);
    float4 a4[4], t4[4];
    #pragma unroll
    for (int i = 0; i < 4; ++i) {
        a4[i] = ((const float4*)anchors)[n0 + i];
        t4[i] = ((const float4*)bbox_targets)[n0 + i];
    }
    cls5x4(B, xm, ns);

    // geometry + this quarter's DFL distance
    float cx[4], cy[4], tx0[4], ty0[4], tx1[4], ty1[4], dk[4];
    #pragma unroll
    for (int i = 0; i < 4; ++i) {
        cx[i]  = 0.5f * (a4[i].x + a4[i].z) * inv_str;
        cy[i]  = 0.5f * (a4[i].y + a4[i].w) * inv_str;
        tx0[i] = t4[i].x * inv_str; ty0[i] = t4[i].y * inv_str;
        tx1[i] = t4[i].z * inv_str; ty1[i] = t4[i].w * inv_str;
        dk[i] = (q == 0) ? (cx[i] - tx0[i]) :
                (q == 1) ? (cy[i] - ty0[i]) :
                (q == 2) ? (tx1[i] - cx[i]) : (ty1[i] - cy[i]);
    }

    float cor[4], ds[4] = {0.0f, 0.0f, 0.0f, 0.0f};
    box8x4(X, dk, cor, ds);

    // ---- 4-way merge via LDS (SoA float4) ----
    __shared__ float4 s_ns[3][128], s_xm[3][128], s_xl[3][128],
                      s_co[3][128], s_ds[3][128];
    if (q != 0) {
        s_ns[q - 1][g] = make_float4(ns[0], ns[1], ns[2], ns[3]);
        s_xm[q - 1][g] = make_float4(xm[0], xm[1], xm[2], xm[3]);
        s_xl[q - 1][g] = make_float4(xlab[0], xlab[1], xlab[2], xlab[3]);
        s_co[q - 1][g] = make_float4(cor[0], cor[1], cor[2], cor[3]);
        s_ds[q - 1][g] = make_float4(ds[0], ds[1], ds[2], ds[3]);
    }
    __syncthreads();

    float v0 = 0.0f, v1 = 0.0f, v2 = 0.0f, v3 = 0.0f;
    if (q == 0) {
        const float4 lw4 = *(const float4*)(label_weights + n0);
        const float lwv[4] = {lw4.x, lw4.y, lw4.z, lw4.w};
        const float4 nsq[3] = {s_ns[0][g], s_ns[1][g], s_ns[2][g]};
        const float4 xmq[3] = {s_xm[0][g], s_xm[1][g], s_xm[2][g]};
        const float4 xlq[3] = {s_xl[0][g], s_xl[1][g], s_xl[2][g]};
        const float4 coq[3] = {s_co[0][g], s_co[1][g], s_co[2][g]};
        const float4 dsq[3] = {s_ds[0][g], s_ds[1][g], s_ds[2][g]};

        #pragma unroll
        for (int i = 0; i < 4; ++i) {
            const float nsv[4] = {i==0?nsq[0].x:i==1?nsq[0].y:i==2?nsq[0].z:nsq[0].w,
                                  i==0?nsq[1].x:i==1?nsq[1].y:i==2?nsq[1].z:nsq[1].w,
                                  i==0?nsq[2].x:i==1?nsq[2].y:i==2?nsq[2].z:nsq[2].w, 0.f};
            const float xmv[3] = {i==0?xmq[0].x:i==1?xmq[0].y:i==2?xmq[0].z:xmq[0].w,
                                  i==0?xmq[1].x:i==1?xmq[1].y:i==2?xmq[1].z:xmq[1].w,
                                  i==0?xmq[2].x:i==1?xmq[2].y:i==2?xmq[2].z:xmq[2].w};
            const float xlv[3] = {i==0?xlq[0].x:i==1?xlq[0].y:i==2?xlq[0].z:xlq[0].w,
                                  i==0?xlq[1].x:i==1?xlq[1].y:i==2?xlq[1].z:xlq[1].w,
                                  i==0?xlq[2].x:i==1?xlq[2].y:i==2?xlq[2].z:xlq[2].w};
            const float cov[3] = {i==0?coq[0].x:i==1?coq[0].y:i==2?coq[0].z:coq[0].w,
                                  i==0?coq[1].x:i==1?coq[1].y:i==2?coq[1].z:coq[1].w,
                                  i==0?coq[2].x:i==1?coq[2].y:i==2?coq[2].z:coq[2].w};
            const float dsv[3] = {i==0?dsq[0].x:i==1?dsq[0].y:i==2?dsq[0].z:dsq[0].w,
                                  i==0?dsq[1].x:i==1?dsq[1].y:i==2?dsq[1].z:dsq[1].w,
                                  i==0?dsq[2].x:i==1?dsq[2].y:i==2?dsq[2].z:dsq[2].w};

            const int lc = labv[i];
            const bool pos = (lc >= 0) && (lc < NUM_CLASSES);
            const float xmax_all = fmaxf(fmaxf(xm[i], xmv[0]), fmaxf(xmv[1], xmv[2]));
            const float ns_all   = ns[i] + nsv[0] + nsv[1] + nsv[2];
            const int lq = lc / CQ;                       // owning quarter
            const float xl_sel = (lq == 0) ? xlab[i] :
                                 (lq == 1) ? xlv[0] :
                                 (lq == 2) ? xlv[1] : xlv[2];
            const float ds_all = ds[i] + dsv[0] + dsv[1] + dsv[2];
            const float c0 = cor[i], c1 = cov[0], c2 = cov[1], c3 = cov[2];

            const float wt = pos ? frcp(1.0f + fexp(-xmax_all)) : 0.0f;

            const float px0 = cx[i] - c0, py0 = cy[i] - c1;
            const float px1 = cx[i] + c2, py1 = cy[i] + c3;

            const float ilx = fmaxf(px0, tx0[i]), ily = fmaxf(py0, ty0[i]);
            const float irx = fminf(px1, tx1[i]), iry = fminf(py1, ty1[i]);
            const float iw = fmaxf(irx - ilx, 0.0f), ih = fmaxf(iry - ily, 0.0f);
            const float overlap = iw * ih;
            const float ap = (px1 - px0) * (py1 - py0);
            const float at = (tx1[i] - tx0[i]) * (ty1[i] - ty0[i]);
            const float uni = fmaxf(ap + at - overlap, 1e-6f);
            const float iou = overlap * frcp(uni);

            const float elx = fminf(px0, tx0[i]), ely = fminf(py0, ty0[i]);
            const float erx = fmaxf(px1, tx1[i]), ery = fmaxf(py1, ty1[i]);
            const float ew = fmaxf(erx - elx, 0.0f), eh = fmaxf(ery - ely, 0.0f);
            const float earea = fmaxf(ew * eh, 1e-6f);
            const float giou = iou - (earea - uni) * frcp(earea);

            const float score = pos ? iou : 0.0f;
            float row = ns_all;
            if (pos) {
                const float ee = fexp(-xl_sel);
                const float s  = frcp(1.0f + ee);      // sigmoid(x_label)
                const float sp = xl_sel - flog(s);     // softplus(x_label)
                const float negterm = sp * s * s;
                const float sf = score - s;
                const float posl = (sp - xl_sel * score) * sf * sf;
                row = row - negterm + posl;
            }

            v0 += row * lwv[i];
            v1 += (1.0f - giou) * wt;
            v2 += ds_all * wt;
            v3 += wt;
        }
    }

    v0 *= inv_nts;
    v1 *= 2.0f;
    v2 *= 0.0625f;     // 0.25 / 4

    // ---------------- reduction ----------------
    #pragma unroll
    for (int off = 32; off > 0; off >>= 1) {
        v0 += __shfl_down(v0, off);
        v1 += __shfl_down(v1, off);
        v2 += __shfl_down(v2, off);
        v3 += __shfl_down(v3, off);
    }

    __shared__ float smr[8][4];   // [wave][channel]
    const int w    = tib >> 6;
    const int lane = tib & 63;
    if (lane == 0) {
        smr[w][0] = v0; smr[w][1] = v1;
        smr[w][2] = v2; smr[w][3] = v3;
    }
    __syncthreads();
    if (tib == 0) {
        float s0 = 0.0f, s1 = 0.0f, s2 = 0.0f, s3 = 0.0f;
        #pragma unroll
        for (int i = 0; i < 8; ++i) {
            s0 += smr[i][0]; s1 += smr[i][1];
            s2 += smr[i][2]; s3 += smr[i][3];
        }
        atomicAdd(&out[0], s0);
        atomicAdd(&out[1], s1);
        atomicAdd(&out[2], s2);
        atomicAdd(&out[3], s3);
    }
}

extern "C" void kernel_launch(void* const* d_in, const int* in_sizes, int n_in,
                              void* d_out, int out_size, void* d_ws, size_t ws_size,
                              hipStream_t stream) {
    const float* anchors       = (const float*)d_in[0];
    const float* cls_score     = (const float*)d_in[1];
    const float* bbox_pred     = (const float*)d_in[2];
    const float* label_weights = (const float*)d_in[3];
    const float* bbox_targets  = (const float*)d_in[4];
    const int*   labels        = (const int*)d_in[5];
    const int*   nts_p         = (const int*)d_in[6];
    const int*   stride_p      = (const int*)d_in[7];
    float* out = (float*)d_out;

    const int N = in_sizes[5];  // labels count = B*H*W

    hipMemsetAsync(d_out, 0, 4 * sizeof(float), stream);

    const int grid = N / APB;                 // 512 blocks -> 2 blocks/CU
    nanodet_loss_kernel<<<grid, BLOCK, 0, stream>>>(
        anchors, cls_score, bbox_pred, label_weights, bbox_targets,
        labels, nts_p, stride_p, out);
}

// Round 10
// 57.702 us; speedup vs baseline: 1.3148x; 1.3148x over previous
//
#include <hip/hip_runtime.h>

#define NUM_CLASSES 80
#define CQ 20           // cls channels per quarter
#define R1 8            // REG_MAX + 1
#define HW 4096         // H*W
#define BLOCK 512       // 4 quarters x 128 threads
#define APB 512         // anchors per block (128 groups x 4 anchors)

// fast hardware transcendentals (outputs are sums of 262K O(1) terms,
// absmax threshold 122.88 -- 2-ulp native math is noise)
__device__ __forceinline__ float fexp(float x) { return __expf(x); }
__device__ __forceinline__ float flog(float x) { return __logf(x); }
__device__ __forceinline__ float frcp(float x) { return __builtin_amdgcn_rcpf(x); }

// NCH channel-strided float4 loads (16 B/lane = 1 KB/wave-load).
template<int C0, int NCH>
__device__ __forceinline__ void ldn(float4 (&d)[NCH], const float* __restrict__ u,
                                    uint32_t e) {
    #pragma unroll
    for (int j = 0; j < NCH; ++j)
        d[j] = *reinterpret_cast<const float4*>(u + (uint32_t)((C0 + j) * HW) + e);
}

__device__ __forceinline__ void cls1(float x, float& xm, float& ns) {
    xm = fmaxf(xm, x);
    float e  = fexp(-x);            // exp(-x)
    float s  = frcp(1.0f + e);      // sigmoid
    float sp = x - flog(s);         // softplus(x)
    ns = fmaf(sp * s, s, ns);
}

// 5 channels x 4 anchors; all indices compile-time
__device__ __forceinline__ void cls5x4(const float4 (&d)[5],
                                       float (&xm)[4], float (&ns)[4]) {
    #pragma unroll
    for (int j = 0; j < 5; ++j) {
        cls1(d[j].x, xm[0], ns[0]);
        cls1(d[j].y, xm[1], ns[1]);
        cls1(d[j].z, xm[2], ns[2]);
        cls1(d[j].w, xm[3], ns[3]);
    }
}

// one bbox side for one anchor from two 4-channel chunks
__device__ __forceinline__ void box8(const float (&xa)[4], const float (&xb)[4],
                                     float dk, float& corner, float& dsum) {
    float xk[8] = {xa[0], xa[1], xa[2], xa[3], xb[0], xb[1], xb[2], xb[3]};
    float m = -INFINITY;
    #pragma unroll
    for (int j = 0; j < 8; ++j) m = fmaxf(m, xk[j]);
    float se = 0.0f, swe = 0.0f;
    #pragma unroll
    for (int j = 0; j < 8; ++j) {
        float e = fexp(xk[j] - m);
        se += e;
        swe = fmaf(e, (float)j, swe);
    }
    corner = swe * frcp(se);
    const float lse = m + flog(se);     // logsumexp

    // DFL: runtime bin -> unrolled compare-select (no scratch)
    float d = fminf(fmaxf(dk, 0.0f), (float)(R1 - 1) - 0.1f);
    int tl = (int)d;                    // d >= 0: floor == trunc
    int tr = tl + 1; if (tr > R1 - 1) tr = R1 - 1;
    float x_tl = xk[0], x_tr = xk[0];
    #pragma unroll
    for (int j = 1; j < 8; ++j) {
        if (j == tl) x_tl = xk[j];
        if (j == tr) x_tr = xk[j];
    }
    dsum += (lse - x_tl) * ((float)(tl + 1) - d) + (lse - x_tr) * (d - (float)tl);
}

__global__ __launch_bounds__(BLOCK)
__attribute__((amdgpu_waves_per_eu(2, 2)))   // 256-VGPR budget: empirically the
                                             // only setting that unpins the
                                             // allocator from 64 (R7/R8 vs R3/4/6/9)
void nanodet_loss_kernel(
    const float* __restrict__ anchors,       // [N,4]
    const float* __restrict__ cls_score,     // [B,C,H,W]
    const float* __restrict__ bbox_pred,     // [B,4*R1,H,W]
    const float* __restrict__ label_weights, // [N]
    const float* __restrict__ bbox_targets,  // [N,4]
    const int*   __restrict__ labels,        // [N]
    const int*   __restrict__ nts_p,         // [1]
    const int*   __restrict__ stride_p,      // [1]
    float* __restrict__ out)
{
    const int tib = threadIdx.x;
    const int q   = tib >> 7;                // quarter: cls [20q,20q+20), side q
    const int g   = tib & 127;               // anchor group in block
    const int blk = blockIdx.x;
    const int b   = blk >> 3;                // image (uniform per block)
    const int hw0 = (blk & 7) * APB;         // window start (uniform)
    const int e   = 4 * g;                   // element offset in window
    const int n0  = blk * APB + e;           // first of this thread's 4 anchors

    const float inv_str = frcp((float)stride_p[0]);
    const float inv_nts = frcp((float)nts_p[0]);

    // quarter-uniform bases (SGPR) + per-thread element offset
    const float* cls_q = cls_score + (size_t)b * NUM_CLASSES * HW
                                   + (size_t)(q * CQ) * HW + hw0;
    const float* box_q = bbox_pred + (size_t)b * (4 * R1) * HW
                                   + (size_t)(q * R1) * HW + hw0;
    const uint32_t ue = (uint32_t)e;

    // ---- early scalar loads ----
    const int4 lab4 = *(const int4*)(labels + n0);
    int labv[4] = {lab4.x, lab4.y, lab4.z, lab4.w};

    // label-logit gather (this quarter's channel range, else dummy ch 0)
    float xlab[4];
    #pragma unroll
    for (int i = 0; i < 4; ++i) {
        const int lc = labv[i];
        const bool own = (lc >= q * CQ) && (lc < (q + 1) * CQ) && (lc < NUM_CLASSES);
        const int ch = own ? (lc - q * CQ) : 0;
        xlab[i] = cls_q[(uint32_t)ch * HW + ue + i];
    }

    // ---- cls pipeline: 4 phases x 5 channels, 2 buffers ----
    float4 A[5], B[5];
    float xm[4] = {-INFINITY, -INFINITY, -INFINITY, -INFINITY};
    float ns[4] = {0.0f, 0.0f, 0.0f, 0.0f};

    ldn<0, 5>(A, cls_q, ue);
    ldn<5, 5>(B, cls_q, ue);
    cls5x4(A, xm, ns);  ldn<10, 5>(A, cls_q, ue);
    cls5x4(B, xm, ns);  ldn<15, 5>(B, cls_q, ue);
    cls5x4(A, xm, ns);

    // issue this quarter's bbox side (two 4-channel chunks) + geometry loads;
    // latency hides under the last cls phase + geometry VALU
    float4 X[4], Y[4];
    ldn<0, 4>(X, box_q, ue);
    ldn<4, 4>(Y, box_q, ue);
    float4 a4[4], t4[4];
    #pragma unroll
    for (int i = 0; i < 4; ++i) {
        a4[i] = ((const float4*)anchors)[n0 + i];
        t4[i] = ((const float4*)bbox_targets)[n0 + i];
    }
    cls5x4(B, xm, ns);

    // geometry + this quarter's DFL distance
    float cx[4], cy[4], tx0[4], ty0[4], tx1[4], ty1[4], dk[4];
    #pragma unroll
    for (int i = 0; i < 4; ++i) {
        cx[i]  = 0.5f * (a4[i].x + a4[i].z) * inv_str;
        cy[i]  = 0.5f * (a4[i].y + a4[i].w) * inv_str;
        tx0[i] = t4[i].x * inv_str; ty0[i] = t4[i].y * inv_str;
        tx1[i] = t4[i].z * inv_str; ty1[i] = t4[i].w * inv_str;
        dk[i] = (q == 0) ? (cx[i] - tx0[i]) :
                (q == 1) ? (cy[i] - ty0[i]) :
                (q == 2) ? (tx1[i] - cx[i]) : (ty1[i] - cy[i]);
    }

    float cor[4], ds[4] = {0.0f, 0.0f, 0.0f, 0.0f};
    {
        float xa[4], xb[4];
        #pragma unroll
        for (int j = 0; j < 4; ++j) { xa[j] = X[j].x; xb[j] = Y[j].x; }
        box8(xa, xb, dk[0], cor[0], ds[0]);
        #pragma unroll
        for (int j = 0; j < 4; ++j) { xa[j] = X[j].y; xb[j] = Y[j].y; }
        box8(xa, xb, dk[1], cor[1], ds[1]);
        #pragma unroll
        for (int j = 0; j < 4; ++j) { xa[j] = X[j].z; xb[j] = Y[j].z; }
        box8(xa, xb, dk[2], cor[2], ds[2]);
        #pragma unroll
        for (int j = 0; j < 4; ++j) { xa[j] = X[j].w; xb[j] = Y[j].w; }
        box8(xa, xb, dk[3], cor[3], ds[3]);
    }

    // ---- 4-way merge via LDS (SoA float4) ----
    __shared__ float4 s_ns[3][128], s_xm[3][128], s_xl[3][128],
                      s_co[3][128], s_ds[3][128];
    if (q != 0) {
        s_ns[q - 1][g] = make_float4(ns[0], ns[1], ns[2], ns[3]);
        s_xm[q - 1][g] = make_float4(xm[0], xm[1], xm[2], xm[3]);
        s_xl[q - 1][g] = make_float4(xlab[0], xlab[1], xlab[2], xlab[3]);
        s_co[q - 1][g] = make_float4(cor[0], cor[1], cor[2], cor[3]);
        s_ds[q - 1][g] = make_float4(ds[0], ds[1], ds[2], ds[3]);
    }
    __syncthreads();

    float v0 = 0.0f, v1 = 0.0f, v2 = 0.0f, v3 = 0.0f;
    if (q == 0) {
        const float4 lw4 = *(const float4*)(label_weights + n0);
        const float lwv[4] = {lw4.x, lw4.y, lw4.z, lw4.w};
        const float4 nsq[3] = {s_ns[0][g], s_ns[1][g], s_ns[2][g]};
        const float4 xmq[3] = {s_xm[0][g], s_xm[1][g], s_xm[2][g]};
        const float4 xlq[3] = {s_xl[0][g], s_xl[1][g], s_xl[2][g]};
        const float4 coq[3] = {s_co[0][g], s_co[1][g], s_co[2][g]};
        const float4 dsq[3] = {s_ds[0][g], s_ds[1][g], s_ds[2][g]};

        #pragma unroll
        for (int i = 0; i < 4; ++i) {
            const float nsv[3] = {i==0?nsq[0].x:i==1?nsq[0].y:i==2?nsq[0].z:nsq[0].w,
                                  i==0?nsq[1].x:i==1?nsq[1].y:i==2?nsq[1].z:nsq[1].w,
                                  i==0?nsq[2].x:i==1?nsq[2].y:i==2?nsq[2].z:nsq[2].w};
            const float xmv[3] = {i==0?xmq[0].x:i==1?xmq[0].y:i==2?xmq[0].z:xmq[0].w,
                                  i==0?xmq[1].x:i==1?xmq[1].y:i==2?xmq[1].z:xmq[1].w,
                                  i==0?xmq[2].x:i==1?xmq[2].y:i==2?xmq[2].z:xmq[2].w};
            const float xlv[3] = {i==0?xlq[0].x:i==1?xlq[0].y:i==2?xlq[0].z:xlq[0].w,
                                  i==0?xlq[1].x:i==1?xlq[1].y:i==2?xlq[1].z:xlq[1].w,
                                  i==0?xlq[2].x:i==1?xlq[2].y:i==2?xlq[2].z:xlq[2].w};
            const float cov[3] = {i==0?coq[0].x:i==1?coq[0].y:i==2?coq[0].z:coq[0].w,
                                  i==0?coq[1].x:i==1?coq[1].y:i==2?coq[1].z:coq[1].w,
                                  i==0?coq[2].x:i==1?coq[2].y:i==2?coq[2].z:coq[2].w};
            const float dsv[3] = {i==0?dsq[0].x:i==1?dsq[0].y:i==2?dsq[0].z:dsq[0].w,
                                  i==0?dsq[1].x:i==1?dsq[1].y:i==2?dsq[1].z:dsq[1].w,
                                  i==0?dsq[2].x:i==1?dsq[2].y:i==2?dsq[2].z:dsq[2].w};

            const int lc = labv[i];
            const bool pos = (lc >= 0) && (lc < NUM_CLASSES);
            const float xmax_all = fmaxf(fmaxf(xm[i], xmv[0]), fmaxf(xmv[1], xmv[2]));
            const float ns_all   = ns[i] + nsv[0] + nsv[1] + nsv[2];
            const int lq = lc / CQ;                       // owning quarter
            const float xl_sel = (lq == 0) ? xlab[i] :
                                 (lq == 1) ? xlv[0] :
                                 (lq == 2) ? xlv[1] : xlv[2];
            const float ds_all = ds[i] + dsv[0] + dsv[1] + dsv[2];
            const float c0 = cor[i], c1 = cov[0], c2 = cov[1], c3 = cov[2];

            const float wt = pos ? frcp(1.0f + fexp(-xmax_all)) : 0.0f;

            const float px0 = cx[i] - c0, py0 = cy[i] - c1;
            const float px1 = cx[i] + c2, py1 = cy[i] + c3;

            const float ilx = fmaxf(px0, tx0[i]), ily = fmaxf(py0, ty0[i]);
            const float irx = fminf(px1, tx1[i]), iry = fminf(py1, ty1[i]);
            const float iw = fmaxf(irx - ilx, 0.0f), ih = fmaxf(iry - ily, 0.0f);
            const float overlap = iw * ih;
            const float ap = (px1 - px0) * (py1 - py0);
            const float at = (tx1[i] - tx0[i]) * (ty1[i] - ty0[i]);
            const float uni = fmaxf(ap + at - overlap, 1e-6f);
            const float iou = overlap * frcp(uni);

            const float elx = fminf(px0, tx0[i]), ely = fminf(py0, ty0[i]);
            const float erx = fmaxf(px1, tx1[i]), ery = fmaxf(py1, ty1[i]);
            const float ew = fmaxf(erx - elx, 0.0f), eh = fmaxf(ery - ely, 0.0f);
            const float earea = fmaxf(ew * eh, 1e-6f);
            const float giou = iou - (earea - uni) * frcp(earea);

            const float score = pos ? iou : 0.0f;
            float row = ns_all;
            if (pos) {
                const float ee = fexp(-xl_sel);
                const float s  = frcp(1.0f + ee);      // sigmoid(x_label)
                const float sp = xl_sel - flog(s);     // softplus(x_label)
                const float negterm = sp * s * s;
                const float sf = score - s;
                const float posl = (sp - xl_sel * score) * sf * sf;
                row = row - negterm + posl;
            }

            v0 += row * lwv[i];
            v1 += (1.0f - giou) * wt;
            v2 += ds_all * wt;
            v3 += wt;
        }
    }

    v0 *= inv_nts;
    v1 *= 2.0f;
    v2 *= 0.0625f;     // 0.25 / 4

    // ---------------- reduction ----------------
    #pragma unroll
    for (int off = 32; off > 0; off >>= 1) {
        v0 += __shfl_down(v0, off);
        v1 += __shfl_down(v1, off);
        v2 += __shfl_down(v2, off);
        v3 += __shfl_down(v3, off);
    }

    __shared__ float smr[8][4];   // [wave][channel]
    const int w    = tib >> 6;
    const int lane = tib & 63;
    if (lane == 0) {
        smr[w][0] = v0; smr[w][1] = v1;
        smr[w][2] = v2; smr[w][3] = v3;
    }
    __syncthreads();
    if (tib == 0) {
        float s0 = 0.0f, s1 = 0.0f, s2 = 0.0f, s3 = 0.0f;
        #pragma unroll
        for (int i = 0; i < 8; ++i) {
            s0 += smr[i][0]; s1 += smr[i][1];
            s2 += smr[i][2]; s3 += smr[i][3];
        }
        atomicAdd(&out[0], s0);
        atomicAdd(&out[1], s1);
        atomicAdd(&out[2], s2);
        atomicAdd(&out[3], s3);
    }
}

extern "C" void kernel_launch(void* const* d_in, const int* in_sizes, int n_in,
                              void* d_out, int out_size, void* d_ws, size_t ws_size,
                              hipStream_t stream) {
    const float* anchors       = (const float*)d_in[0];
    const float* cls_score     = (const float*)d_in[1];
    const float* bbox_pred     = (const float*)d_in[2];
    const float* label_weights = (const float*)d_in[3];
    const float* bbox_targets  = (const float*)d_in[4];
    const int*   labels        = (const int*)d_in[5];
    const int*   nts_p         = (const int*)d_in[6];
    const int*   stride_p      = (const int*)d_in[7];
    float* out = (float*)d_out;

    const int N = in_sizes[5];  // labels count = B*H*W

    hipMemsetAsync(d_out, 0, 4 * sizeof(float), stream);

    const int grid = N / APB;                 // 512 blocks -> 2 blocks/CU
    nanodet_loss_kernel<<<grid, BLOCK, 0, stream>>>(
        anchors, cls_score, bbox_pred, label_weights, bbox_targets,
        labels, nts_p, stride_p, out);
}

// Round 11
// 43.621 us; speedup vs baseline: 1.7393x; 1.3228x over previous
//
#include <hip/hip_runtime.h>

#define NUM_CLASSES 80
#define R1 8            // REG_MAX + 1
#define HW 4096         // H*W
#define BLOCK 512       // 2 halves x 256 threads
#define APB 1024        // anchors per block

// fast hardware transcendentals (outputs are sums of 262K O(1) terms,
// absmax threshold 122.88 -- 2-ulp native math is noise)
__device__ __forceinline__ float fexp(float x) { return __expf(x); }
__device__ __forceinline__ float flog(float x) { return __logf(x); }
__device__ __forceinline__ float frcp(float x) { return __builtin_amdgcn_rcpf(x); }

// one full channel window (1024 anchors = 4 KB): the wave's 4 float4 loads are
// CONTIGUOUS (lane l, load j covers anchors 256j + 4l .. +3) -- no stride
// between bursts, unlike the 16 KB-strided ld8 pattern.
__device__ __forceinline__ void ldch(float4 (&d)[4], const float* __restrict__ p,
                                     uint32_t l4) {
    #pragma unroll
    for (int j = 0; j < 4; ++j)
        d[j] = *reinterpret_cast<const float4*>(p + 256u * j + l4);
}

__device__ __forceinline__ void cls1(float x, float& xm, float& ns) {
    xm = fmaxf(xm, x);
    float e  = fexp(-x);            // exp(-x)
    float s  = frcp(1.0f + e);      // sigmoid
    float sp = x - flog(s);         // softplus(x)
    ns = fmaf(sp * s, s, ns);
}

// one channel x 16 anchors (4 groups x 4 lanes); all indices compile-time
__device__ __forceinline__ void clsch(const float4 (&d)[4],
                                      float (&xm)[4][4], float (&ns)[4][4]) {
    #pragma unroll
    for (int j = 0; j < 4; ++j) {
        cls1(d[j].x, xm[j][0], ns[j][0]);
        cls1(d[j].y, xm[j][1], ns[j][1]);
        cls1(d[j].z, xm[j][2], ns[j][2]);
        cls1(d[j].w, xm[j][3], ns[j][3]);
    }
}

// 8 channel-strided float4 loads (box path, as R8)
template<int C0>
__device__ __forceinline__ void ld8(float4 (&d)[8], const float* __restrict__ u,
                                    uint32_t e) {
    #pragma unroll
    for (int j = 0; j < 8; ++j)
        d[j] = *reinterpret_cast<const float4*>(u + (uint32_t)((C0 + j) * HW) + e);
}

// one bbox side for one anchor: softmax-integral corner + DFL term
__device__ __forceinline__ void box8(const float (&xk)[8], float dk,
                                     float& corner, float& dsum) {
    float m = -INFINITY;
    #pragma unroll
    for (int j = 0; j < 8; ++j) m = fmaxf(m, xk[j]);
    float se = 0.0f, swe = 0.0f;
    #pragma unroll
    for (int j = 0; j < 8; ++j) {
        float e = fexp(xk[j] - m);
        se += e;
        swe = fmaf(e, (float)j, swe);
    }
    corner = swe * frcp(se);
    const float lse = m + flog(se);     // logsumexp

    // DFL: runtime bin -> unrolled compare-select (no scratch)
    float d = fminf(fmaxf(dk, 0.0f), (float)(R1 - 1) - 0.1f);
    int tl = (int)d;                    // d >= 0: floor == trunc
    int tr = tl + 1; if (tr > R1 - 1) tr = R1 - 1;
    float x_tl = xk[0], x_tr = xk[0];
    #pragma unroll
    for (int j = 1; j < 8; ++j) {
        if (j == tl) x_tl = xk[j];
        if (j == tr) x_tr = xk[j];
    }
    dsum += (lse - x_tl) * ((float)(tl + 1) - d) + (lse - x_tr) * (d - (float)tl);
}

// one side (8 channels) for 4 anchors
__device__ __forceinline__ void box8x4(const float4 (&d)[8], const float (&dk)[4],
                                       float (&cor)[4], float (&ds)[4]) {
    float xk[8];
    #pragma unroll
    for (int j = 0; j < 8; ++j) xk[j] = d[j].x;
    box8(xk, dk[0], cor[0], ds[0]);
    #pragma unroll
    for (int j = 0; j < 8; ++j) xk[j] = d[j].y;
    box8(xk, dk[1], cor[1], ds[1]);
    #pragma unroll
    for (int j = 0; j < 8; ++j) xk[j] = d[j].z;
    box8(xk, dk[2], cor[2], ds[2]);
    #pragma unroll
    for (int j = 0; j < 8; ++j) xk[j] = d[j].w;
    box8(xk, dk[3], cor[3], ds[3]);
}

__global__ __launch_bounds__(BLOCK)
__attribute__((amdgpu_waves_per_eu(2, 2)))   // 256-VGPR budget (grid caps runtime
                                             // occupancy at 2 waves/SIMD anyway)
void nanodet_loss_kernel(
    const float* __restrict__ anchors,       // [N,4]
    const float* __restrict__ cls_score,     // [B,C,H,W]
    const float* __restrict__ bbox_pred,     // [B,4*R1,H,W]
    const float* __restrict__ label_weights, // [N]
    const float* __restrict__ bbox_targets,  // [N,4]
    const int*   __restrict__ labels,        // [N]
    const int*   __restrict__ nts_p,         // [1]
    const int*   __restrict__ stride_p,      // [1]
    float* __restrict__ out)
{
    const int tib  = threadIdx.x;
    const int h    = tib >> 8;               // half: cls [40h,40h+40), sides 2h,2h+1
    const int u    = tib & 255;              // thread in half
    const int w    = tib >> 6;               // wave 0..7
    const int wh   = w & 3;                  // wave in half
    const int lane = tib & 63;
    const int blk  = blockIdx.x;
    const int b    = blk >> 2;               // image (4 blocks per image)
    const int hw0  = (blk & 3) * APB;        // window start (uniform)
    const int n0   = blk * APB + 4 * u;      // this half-thread's epilogue anchors

    const float inv_str = frcp((float)stride_p[0]);
    const float inv_nts = frcp((float)nts_p[0]);

    const float* cls_h = cls_score + (size_t)b * NUM_CLASSES * HW
                                   + (size_t)(h * 40) * HW + hw0;
    const float* cls_w = cls_h + (size_t)wh * HW;     // this wave's channel base
    const float* box_h = bbox_pred + (size_t)b * (4 * R1) * HW
                                   + (size_t)(h * 2 * R1) * HW + hw0;
    const uint32_t l4 = 4u * (uint32_t)lane;
    const uint32_t ue = 4u * (uint32_t)u;

    // ---- early scalar loads + label-logit gather (epilogue layout) ----
    const int4 lab4 = *(const int4*)(labels + n0);
    int labv[4] = {lab4.x, lab4.y, lab4.z, lab4.w};
    float xlab[4];
    #pragma unroll
    for (int i = 0; i < 4; ++i) {
        const int lc = labv[i];
        const bool own = (lc >= h * 40) && (lc < h * 40 + 40);
        const int ch = own ? (lc - h * 40) : 0;
        xlab[i] = cls_h[(uint32_t)ch * HW + ue + i];
    }

    // ---- cls sweep: 10 channels/wave (wh + 4k), 4 KB contiguous per channel ----
    float4 P[4], Q[4];
    float xm[4][4], ns[4][4];
    #pragma unroll
    for (int j = 0; j < 4; ++j)
        #pragma unroll
        for (int i = 0; i < 4; ++i) { xm[j][i] = -INFINITY; ns[j][i] = 0.0f; }

    ldch(P, cls_w + (size_t)0 * 4 * HW, l4);
    ldch(Q, cls_w + (size_t)1 * 4 * HW, l4);
    clsch(P, xm, ns);  ldch(P, cls_w + (size_t)2 * 4 * HW, l4);
    clsch(Q, xm, ns);  ldch(Q, cls_w + (size_t)3 * 4 * HW, l4);
    clsch(P, xm, ns);  ldch(P, cls_w + (size_t)4 * 4 * HW, l4);
    clsch(Q, xm, ns);  ldch(Q, cls_w + (size_t)5 * 4 * HW, l4);
    clsch(P, xm, ns);  ldch(P, cls_w + (size_t)6 * 4 * HW, l4);
    clsch(Q, xm, ns);  ldch(Q, cls_w + (size_t)7 * 4 * HW, l4);
    clsch(P, xm, ns);  ldch(P, cls_w + (size_t)8 * 4 * HW, l4);
    clsch(Q, xm, ns);  ldch(Q, cls_w + (size_t)9 * 4 * HW, l4);
    clsch(P, xm, ns);

    // issue box + geometry loads now; latency hides under last phase + merge
    float4 Xs[8], Ys[8];
    ld8<0>(Xs, box_h, ue);              // side 2h
    ld8<8>(Ys, box_h, ue);              // side 2h+1
    float4 a4[4], t4[4];
    #pragma unroll
    for (int i = 0; i < 4; ++i) {
        a4[i] = ((const float4*)anchors)[n0 + i];
        t4[i] = ((const float4*)bbox_targets)[n0 + i];
    }
    clsch(Q, xm, ns);

    // ---- 8-wave cls merge via LDS (rows 0-7 ns, rows 8-15 xm) ----
    __shared__ float tmp[16 * APB];      // 64 KB
    #pragma unroll
    for (int j = 0; j < 4; ++j) {
        *(float4*)&tmp[(unsigned)w * APB + 256u * j + l4] =
            make_float4(ns[j][0], ns[j][1], ns[j][2], ns[j][3]);
        *(float4*)&tmp[(unsigned)(8 + w) * APB + 256u * j + l4] =
            make_float4(xm[j][0], xm[j][1], xm[j][2], xm[j][3]);
    }
    __syncthreads();
    {
        // each thread merges 2 anchors (column-wise ownership -> no hazards)
        #pragma unroll
        for (int i = 0; i < 2; ++i) {
            const int a = 2 * tib + i;
            float sns = tmp[a];
            float sxm = tmp[8 * APB + a];
            #pragma unroll
            for (int r = 1; r < 8; ++r) {
                sns += tmp[r * APB + a];
                sxm = fmaxf(sxm, tmp[(8 + r) * APB + a]);
            }
            tmp[a]           = sns;      // row 0 <- merged negsum
            tmp[8 * APB + a] = sxm;      // row 8 <- merged xmax
        }
    }
    __syncthreads();

    // ---- geometry + box compute (R8 path) ----
    float cx[4], cy[4], tx0[4], ty0[4], tx1[4], ty1[4], dk0[4], dk1[4];
    #pragma unroll
    for (int i = 0; i < 4; ++i) {
        cx[i]  = 0.5f * (a4[i].x + a4[i].z) * inv_str;
        cy[i]  = 0.5f * (a4[i].y + a4[i].w) * inv_str;
        tx0[i] = t4[i].x * inv_str; ty0[i] = t4[i].y * inv_str;
        tx1[i] = t4[i].z * inv_str; ty1[i] = t4[i].w * inv_str;
        dk0[i] = (h == 0) ? (cx[i] - tx0[i]) : (tx1[i] - cx[i]);
        dk1[i] = (h == 0) ? (cy[i] - ty0[i]) : (ty1[i] - cy[i]);
    }
    float corA[4], corB[4], ds[4] = {0.0f, 0.0f, 0.0f, 0.0f};
    box8x4(Xs, dk0, corA, ds);
    box8x4(Ys, dk1, corB, ds);

    // ---- cross-half box/xlab merge ----
    __shared__ float4 s_xl[256], s_cA[256], s_cB[256], s_ds[256];
    if (h == 1) {
        s_xl[u] = make_float4(xlab[0], xlab[1], xlab[2], xlab[3]);
        s_cA[u] = make_float4(corA[0], corA[1], corA[2], corA[3]);
        s_cB[u] = make_float4(corB[0], corB[1], corB[2], corB[3]);
        s_ds[u] = make_float4(ds[0], ds[1], ds[2], ds[3]);
    }
    __syncthreads();

    float v0 = 0.0f, v1 = 0.0f, v2 = 0.0f, v3 = 0.0f;
    if (h == 0) {
        const float4 lw4 = *(const float4*)(label_weights + n0);
        const float lwv[4] = {lw4.x, lw4.y, lw4.z, lw4.w};
        const float4 q_xl = s_xl[u], q_cA = s_cA[u], q_cB = s_cB[u], q_ds = s_ds[u];
        const float xl1[4] = {q_xl.x, q_xl.y, q_xl.z, q_xl.w};
        const float c2a[4] = {q_cA.x, q_cA.y, q_cA.z, q_cA.w};
        const float c3a[4] = {q_cB.x, q_cB.y, q_cB.z, q_cB.w};
        const float ds1[4] = {q_ds.x, q_ds.y, q_ds.z, q_ds.w};

        #pragma unroll
        for (int i = 0; i < 4; ++i) {
            const int a = 4 * u + i;                 // anchor in block window
            const float ns_all = tmp[a];
            const float xm_all = tmp[8 * APB + a];
            const int lc = labv[i];
            const bool pos = (lc >= 0) && (lc < NUM_CLASSES);
            const float xl_sel = (lc < 40) ? xlab[i] : xl1[i];
            const float ds_all = ds[i] + ds1[i];

            const float wt = pos ? frcp(1.0f + fexp(-xm_all)) : 0.0f;

            const float px0 = cx[i] - corA[i], py0 = cy[i] - corB[i];
            const float px1 = cx[i] + c2a[i],  py1 = cy[i] + c3a[i];

            const float ilx = fmaxf(px0, tx0[i]), ily = fmaxf(py0, ty0[i]);
            const float irx = fminf(px1, tx1[i]), iry = fminf(py1, ty1[i]);
            const float iw = fmaxf(irx - ilx, 0.0f), ih = fmaxf(iry - ily, 0.0f);
            const float overlap = iw * ih;
            const float ap = (px1 - px0) * (py1 - py0);
            const float at = (tx1[i] - tx0[i]) * (ty1[i] - ty0[i]);
            const float uni = fmaxf(ap + at - overlap, 1e-6f);
            const float iou = overlap * frcp(uni);

            const float elx = fminf(px0, tx0[i]), ely = fminf(py0, ty0[i]);
            const float erx = fmaxf(px1, tx1[i]), ery = fmaxf(py1, ty1[i]);
            const float ew = fmaxf(erx - elx, 0.0f), eh = fmaxf(ery - ely, 0.0f);
            const float earea = fmaxf(ew * eh, 1e-6f);
            const float giou = iou - (earea - uni) * frcp(earea);

            const float score = pos ? iou : 0.0f;
            float row = ns_all;
            if (pos) {
                const float ee = fexp(-xl_sel);
                const float s  = frcp(1.0f + ee);      // sigmoid(x_label)
                const float sp = xl_sel - flog(s);     // softplus(x_label)
                const float negterm = sp * s * s;
                const float sf = score - s;
                const float posl = (sp - xl_sel * score) * sf * sf;
                row = row - negterm + posl;
            }

            v0 += row * lwv[i];
            v1 += (1.0f - giou) * wt;
            v2 += ds_all * wt;
            v3 += wt;
        }
    }

    v0 *= inv_nts;
    v1 *= 2.0f;
    v2 *= 0.0625f;     // 0.25 / 4

    // ---------------- reduction ----------------
    #pragma unroll
    for (int off = 32; off > 0; off >>= 1) {
        v0 += __shfl_down(v0, off);
        v1 += __shfl_down(v1, off);
        v2 += __shfl_down(v2, off);
        v3 += __shfl_down(v3, off);
    }

    __shared__ float smr[8][4];   // [wave][channel]
    if (lane == 0) {
        smr[w][0] = v0; smr[w][1] = v1;
        smr[w][2] = v2; smr[w][3] = v3;
    }
    __syncthreads();
    if (tib == 0) {
        float s0 = 0.0f, s1 = 0.0f, s2 = 0.0f, s3 = 0.0f;
        #pragma unroll
        for (int i = 0; i < 8; ++i) {
            s0 += smr[i][0]; s1 += smr[i][1];
            s2 += smr[i][2]; s3 += smr[i][3];
        }
        atomicAdd(&out[0], s0);
        atomicAdd(&out[1], s1);
        atomicAdd(&out[2], s2);
        atomicAdd(&out[3], s3);
    }
}

extern "C" void kernel_launch(void* const* d_in, const int* in_sizes, int n_in,
                              void* d_out, int out_size, void* d_ws, size_t ws_size,
                              hipStream_t stream) {
    const float* anchors       = (const float*)d_in[0];
    const float* cls_score     = (const float*)d_in[1];
    const float* bbox_pred     = (const float*)d_in[2];
    const float* label_weights = (const float*)d_in[3];
    const float* bbox_targets  = (const float*)d_in[4];
    const int*   labels        = (const int*)d_in[5];
    const int*   nts_p         = (const int*)d_in[6];
    const int*   stride_p      = (const int*)d_in[7];
    float* out = (float*)d_out;

    const int N = in_sizes[5];  // labels count = B*H*W

    hipMemsetAsync(d_out, 0, 4 * sizeof(float), stream);

    const int grid = N / APB;                 // 256 blocks
    nanodet_loss_kernel<<<grid, BLOCK, 0, stream>>>(
        anchors, cls_score, bbox_pred, label_weights, bbox_targets,
        labels, nts_p, stride_p, out);
}